// Round 1
// baseline (152.645 us; speedup 1.0000x reference)
//
#include <hip/hip_runtime.h>

// Path signature, depth 4: B=32, L=1024, d=8, fp32.
// Levels: S1(8) S2(64) S3(512) S4(4096) per batch; sig stride 4680 floats.
//
// Kernel 1: one wave per chunk of 32 increments; full signature state in
//   registers with lane l=(i*8+j) owning S4[i][j][:][:], S3[i][j][:], S2[i][j],
//   S1[i]. Horner-factored update S_new = S_old (x) exp(w).
// Kernel 2: one 1024-thread workgroup per batch; 5-round in-place Chen binary
//   tree over the 32 chunk signatures in d_ws; final round writes d_out.

#define D 8
#define LPATH 1024
#define NINC 1023
#define BATCH 32
#define CHUNKS 32
#define MSTEP 32
#define SIG_STRIDE 4680
#define OFF2 8
#define OFF3 72
#define OFF4 584

__device__ __forceinline__ float readlane_f(float v, int l) {
  return __builtin_bit_cast(float, __builtin_amdgcn_readlane(__builtin_bit_cast(int, v), l));
}

__device__ __forceinline__ void load8(const float* __restrict__ p, float* dst) {
  float4 lo = *(const float4*)p;
  float4 hi = *(const float4*)(p + 4);
  dst[0] = lo.x; dst[1] = lo.y; dst[2] = lo.z; dst[3] = lo.w;
  dst[4] = hi.x; dst[5] = hi.y; dst[6] = hi.z; dst[7] = hi.w;
}

__device__ __forceinline__ void store8(float* __restrict__ p, const float* src) {
  *(float4*)p       = make_float4(src[0], src[1], src[2], src[3]);
  *(float4*)(p + 4) = make_float4(src[4], src[5], src[6], src[7]);
}

// ---------------- Kernel 1: per-chunk signature (one wave per chunk) --------
__global__ __launch_bounds__(256) void sig_chunk(const float* __restrict__ path,
                                                 float* __restrict__ ws) {
  const int gwave = (blockIdx.x * 256 + threadIdx.x) >> 6;  // 0..1023
  const int lane  = threadIdx.x & 63;
  const int b = gwave >> 5;
  const int c = gwave & (CHUNKS - 1);
  const int i = lane >> 3;
  const int j = lane & 7;

  const float* __restrict__ p = path + (size_t)b * (LPATH * D);
  const int g0 = c * MSTEP;

  float pc = p[g0 * D + j];  // running previous path value, column j

  float s1 = 0.f, s2 = 0.f;
  float s3[D];
  float s4[D][D];
#pragma unroll
  for (int k = 0; k < D; ++k) {
    s3[k] = 0.f;
#pragma unroll
    for (int m = 0; m < D; ++m) s4[k][m] = 0.f;
  }

  for (int t = 0; t < MSTEP; ++t) {
    int nidx = g0 + t + 1;
    nidx = nidx > NINC ? NINC : nidx;  // clamp -> zero increment (identity)
    float pn = p[nidx * D + j];
    float wj = pn - pc;  // increment component j (wave-uniform row w[0..7])
    pc = pn;
    float wi = __shfl(wj, i, 64);  // w[i]: lane i holds w[i]
    float wm[D];
#pragma unroll
    for (int m = 0; m < D; ++m) wm[m] = readlane_f(wj, m);  // SGPR row

    // ---- level 4 (uses old s1,s2,s3):
    // S4 += S3(x)w + S2(x)w^2/2 + S1(x)w^3/6 + w^4/24 via Horner
    float b1  = __builtin_fmaf(wi, 0.25f, s1);
    float b2  = __builtin_fmaf(b1, wj * (1.f / 3.f), s2);
    float hb2 = b2 * 0.5f;
    float b3[D];
#pragma unroll
    for (int k = 0; k < D; ++k) b3[k] = __builtin_fmaf(hb2, wm[k], s3[k]);
#pragma unroll
    for (int k = 0; k < D; ++k)
#pragma unroll
      for (int m = 0; m < D; ++m)
        s4[k][m] = __builtin_fmaf(b3[k], wm[m], s4[k][m]);

    // ---- level 3 (old s1,s2)
    float c1 = __builtin_fmaf(wi, (1.f / 3.f), s1);
    float c2 = __builtin_fmaf(c1, wj * 0.5f, s2);
#pragma unroll
    for (int k = 0; k < D; ++k) s3[k] = __builtin_fmaf(c2, wm[k], s3[k]);

    // ---- level 2 (old s1), level 1
    float d1 = __builtin_fmaf(wi, 0.5f, s1);
    s2 = __builtin_fmaf(d1, wj, s2);
    s1 += wi;
  }

  float* __restrict__ slot = ws + (size_t)(b * CHUNKS + c) * SIG_STRIDE;
  if (j == 0) slot[i] = s1;
  slot[OFF2 + lane] = s2;
  store8(slot + OFF3 + lane * 8, s3);
#pragma unroll
  for (int k = 0; k < D; ++k) store8(slot + OFF4 + lane * 64 + k * 8, s4[k]);
}

// ---------------- Kernel 2: Chen binary tree within each batch --------------
__global__ __launch_bounds__(1024) void sig_combine(float* __restrict__ ws,
                                                    float* __restrict__ out) {
  const int b    = blockIdx.x;          // 32 batches
  const int wv   = threadIdx.x >> 6;    // 0..15 waves
  const int lane = threadIdx.x & 63;
  const int i = lane >> 3;
  const int j = lane & 7;
  float* __restrict__ base = ws + (size_t)b * CHUNKS * SIG_STRIDE;

  for (int r = 0; r < 5; ++r) {
    const int pairs  = 16 >> r;
    const int stride = 1 << r;
    if (wv < pairs) {
      float* __restrict__ A        = base + (size_t)(wv * 2 * stride) * SIG_STRIDE;
      const float* __restrict__ Bp = A + (size_t)stride * SIG_STRIDE;

      float a1i = A[i];
      float b1j = Bp[j];
      float b1i = __shfl(b1j, i, 64);
      float sb1[D];
#pragma unroll
      for (int m = 0; m < D; ++m) sb1[m] = readlane_f(b1j, m);

      float a2    = A[OFF2 + lane];
      float b2own = Bp[OFF2 + lane];
      float a3[D], b3own[D], b2row[D];
      load8(A + OFF3 + lane * 8, a3);
      load8(Bp + OFF3 + lane * 8, b3own);
      load8(Bp + OFF2 + j * 8, b2row);  // B2[j][:]

      // C1 = A1 + B1
      float c1 = a1i + b1i;
      // C2[i,j] = A2 + B2 + A1[i]*B1[j]
      float c2 = a2 + b2own + a1i * b1j;
      // C3[i,j,k] = A3 + B3 + A1[i]*B2[j,k] + A2[i,j]*B1[k]
      float c3[D];
#pragma unroll
      for (int k = 0; k < D; ++k) {
        float t = __builtin_fmaf(a1i, b2row[k], a3[k] + b3own[k]);
        c3[k] = __builtin_fmaf(a2, sb1[k], t);
      }
      // C4[i,j,k,m] = A4 + B4 + A3[i,j,k]*B1[m] + A2[i,j]*B2[k,m] + A1[i]*B3[j,k,m]
      float acc[D][D];
#pragma unroll
      for (int k = 0; k < D; ++k) {
        float a4[D], b4[D], b2k[D], b3k[D];
        load8(A + OFF4 + lane * 64 + k * 8, a4);
        load8(Bp + OFF4 + lane * 64 + k * 8, b4);
        load8(Bp + OFF2 + k * 8, b2k);
        load8(Bp + OFF3 + (j * 8 + k) * 8, b3k);
#pragma unroll
        for (int m = 0; m < D; ++m) {
          float t = __builtin_fmaf(a3[k], sb1[m], a4[m] + b4[m]);
          t = __builtin_fmaf(a2, b2k[m], t);
          acc[k][m] = __builtin_fmaf(a1i, b3k[m], t);
        }
      }

      if (r < 4) {
        if (j == 0) A[i] = c1;
        A[OFF2 + lane] = c2;
        store8(A + OFF3 + lane * 8, c3);
#pragma unroll
        for (int k = 0; k < D; ++k) store8(A + OFF4 + lane * 64 + k * 8, acc[k]);
      } else {
        // d_out layout: S1 (32x8) | S2 (32x64) | S3 (32x512) | S4 (32x4096)
        if (j == 0) out[b * 8 + i] = c1;
        out[256 + b * 64 + lane] = c2;
        store8(out + 2304 + b * 512 + lane * 8, c3);
#pragma unroll
        for (int k = 0; k < D; ++k)
          store8(out + 18688 + b * 4096 + lane * 64 + k * 8, acc[k]);
      }
    }
    __syncthreads();  // all threads reach this; orders rounds
  }
}

extern "C" void kernel_launch(void* const* d_in, const int* in_sizes, int n_in,
                              void* d_out, int out_size, void* d_ws, size_t ws_size,
                              hipStream_t stream) {
  const float* path = (const float*)d_in[0];
  // d_in[1] = depth (==4), compile-time specialized.
  float* out = (float*)d_out;
  float* ws  = (float*)d_ws;  // needs 32*32*4680*4 = 19.2 MB

  // 1024 chunk-waves, 4 waves per 256-thread block -> 256 blocks
  sig_chunk<<<dim3(256), dim3(256), 0, stream>>>(path, ws);
  // one workgroup per batch, 16 waves, 5 tree rounds
  sig_combine<<<dim3(BATCH), dim3(1024), 0, stream>>>(ws, out);
}